// Round 15
// baseline (802.491 us; speedup 1.0000x reference)
//
#include <hip/hip_runtime.h>
#include <stdint.h>

typedef unsigned short u16;
typedef unsigned int u32;

typedef __bf16 bf16x8 __attribute__((ext_vector_type(8)));
typedef float f32x4 __attribute__((ext_vector_type(4)));

__device__ __forceinline__ u32 bf_rne(float x) {
  u32 u = __builtin_bit_cast(u32, x);
  return (u + 0x7fffu + ((u >> 16) & 1u)) >> 16;
}
__device__ __forceinline__ float bf_up(u32 us) {
  return __builtin_bit_cast(float, us << 16);
}

using gas_p = const __attribute__((address_space(1))) void*;
using las_p = __attribute__((address_space(3))) void*;
#define GLOAD16(g, l) __builtin_amdgcn_global_load_lds((gas_p)(g), (las_p)(l), 16, 0, 0)

// ---------------- cast fp32 -> bf16, 8 elems/thread ----------------
__global__ __launch_bounds__(256) void cast_bf16_k(const float* __restrict__ in,
                                                   u16* __restrict__ out, int n8) {
  int i = blockIdx.x * 256 + threadIdx.x;
  if (i >= n8) return;
  const float4* p = (const float4*)in;
  float4 a = p[2 * i], b = p[2 * i + 1];
  uint4 o;
  o.x = bf_rne(a.x) | (bf_rne(a.y) << 16);
  o.y = bf_rne(a.z) | (bf_rne(a.w) << 16);
  o.z = bf_rne(b.x) | (bf_rne(b.y) << 16);
  o.w = bf_rne(b.z) | (bf_rne(b.w) << 16);
  ((uint4*)out)[i] = o;
}

// ------------- transpose+cast 1024x1024 fp32 W -> bf16 W^T -------------
__global__ __launch_bounds__(256) void transW_k(const float* __restrict__ W0, const float* __restrict__ W1,
                                                const float* __restrict__ W2, const float* __restrict__ W3,
                                                u16* __restrict__ T0, u16* __restrict__ T1,
                                                u16* __restrict__ T2, u16* __restrict__ T3) {
  __shared__ float t[32][33];
  const float* W;
  u16* T;
  switch (blockIdx.z) {
    case 0: W = W0; T = T0; break;
    case 1: W = W1; T = T1; break;
    case 2: W = W2; T = T2; break;
    default: W = W3; T = T3; break;
  }
  const int tx = threadIdx.x & 31, ty = threadIdx.x >> 5;
  const int bn = blockIdx.x * 32, bk = blockIdx.y * 32;
#pragma unroll
  for (int r = 0; r < 4; ++r)
    t[ty + r * 8][tx] = W[(size_t)(bk + ty + r * 8) * 1024 + bn + tx];
  __syncthreads();
#pragma unroll
  for (int r = 0; r < 4; ++r)
    T[(size_t)(bn + ty + r * 8) * 1024 + bk + tx] = (u16)bf_rne(t[tx][ty + r * 8]);
}

// ---------------- m97-style 128x128 bf16 GEMM, B^T input ----------------
// A: [M,K] bf16 row-major; Bt: [N,K] bf16 row-major; C = A @ Bt^T
template <int F32OUT>
__global__ __launch_bounds__(256) void gemm_bt(const u16* __restrict__ A, const u16* __restrict__ Bt,
                                               void* __restrict__ Cout, const float* __restrict__ bias,
                                               int M, int N, int K) {
  __shared__ alignas(16) u16 As[128 * 32];
  __shared__ alignas(16) u16 Bs[128 * 32];
  const int tid = threadIdx.x;
  const int lane = tid & 63;
  const int wave = tid >> 6;
  const int wr = wave >> 1, wc = wave & 1;
  const int bm = blockIdx.y * 128, bn = blockIdx.x * 128;

  const u16* Ag = A + (size_t)(bm + (tid >> 2)) * K + (tid & 3) * 8;
  const u16* Bg = Bt + (size_t)(bn + (tid >> 2)) * K + (tid & 3) * 8;
  const size_t rowStep = (size_t)64 * K;

  f32x4 acc[4][4];
#pragma unroll
  for (int m = 0; m < 4; ++m)
#pragma unroll
    for (int n = 0; n < 4; ++n) acc[m][n] = (f32x4){0.f, 0.f, 0.f, 0.f};

  char* AsC = (char*)As;
  char* BsC = (char*)Bs;
  const int ldsOff = wave * 1024;

  for (int k0 = 0; k0 < K; k0 += 32) {
    GLOAD16(Ag + k0, AsC + ldsOff);
    GLOAD16(Ag + k0 + rowStep, AsC + 4096 + ldsOff);
    GLOAD16(Bg + k0, BsC + ldsOff);
    GLOAD16(Bg + k0 + rowStep, BsC + 4096 + ldsOff);
    __syncthreads();
    bf16x8 av[4], bv[4];
    const int r16 = lane & 15, kk = (lane >> 4) * 8;
#pragma unroll
    for (int m = 0; m < 4; ++m)
      av[m] = *(const bf16x8*)&As[(wr * 64 + m * 16 + r16) * 32 + kk];
#pragma unroll
    for (int n = 0; n < 4; ++n)
      bv[n] = *(const bf16x8*)&Bs[(wc * 64 + n * 16 + r16) * 32 + kk];
#pragma unroll
    for (int m = 0; m < 4; ++m)
#pragma unroll
      for (int n = 0; n < 4; ++n)
        acc[m][n] = __builtin_amdgcn_mfma_f32_16x16x32_bf16(av[m], bv[n], acc[m][n], 0, 0, 0);
    __syncthreads();
  }

  // C/D layout: col = lane&15, row = (lane>>4)*4 + reg   [measured m89/m91]
  const int colb = bn + wc * 64 + (lane & 15);
  const int rowb = bm + wr * 64 + ((lane >> 4) << 2);
  if (F32OUT) {
    float* Co = (float*)Cout;
#pragma unroll
    for (int n = 0; n < 4; ++n) {
      const int col = colb + n * 16;
      const float bvs = bias[col];
#pragma unroll
      for (int m = 0; m < 4; ++m)
#pragma unroll
        for (int r = 0; r < 4; ++r)
          Co[(size_t)(rowb + m * 16 + r) * N + col] = acc[m][n][r] + bvs;
    }
  } else {
    u16* Co = (u16*)Cout;
#pragma unroll
    for (int n = 0; n < 4; ++n) {
      const int col = colb + n * 16;
#pragma unroll
      for (int m = 0; m < 4; ++m)
#pragma unroll
        for (int r = 0; r < 4; ++r)
          Co[(size_t)(rowb + m * 16 + r) * N + col] = (u16)bf_rne(acc[m][n][r]);
    }
  }
}

// ---------------- per-token 8x8 attention, one wave per token ----------------
// token row = 1024 bf16 = 8 chunks x 128 ch. S[i][j] = s2 * dot(q_i, k_j); softmax over j;
// attn_i = sum_j P[i][j] v_j.  Lane l owns channels (2l, 2l+1); score lane = (i=l>>3, j=l&7).
__global__ __launch_bounds__(256) void attn8_k(const u16* __restrict__ Q, const u16* __restrict__ Kk,
                                               const u16* __restrict__ V, u16* __restrict__ O) {
  __shared__ float qs[4][8][132];
  __shared__ float ks[4][8][132];
  __shared__ float ps[4][64];
  const int w = threadIdx.x >> 6, l = threadIdx.x & 63;
  const size_t tok = (size_t)blockIdx.x * 4 + w;
  const u16* q = Q + tok * 1024;
  const u16* k = Kk + tok * 1024;
  const u16* v = V + tok * 1024;
  float vf0[8], vf1[8];
#pragma unroll
  for (int i = 0; i < 8; ++i) {
    u32 qd = *(const u32*)(q + i * 128 + 2 * l);
    u32 kd = *(const u32*)(k + i * 128 + 2 * l);
    u32 vd = *(const u32*)(v + i * 128 + 2 * l);
    qs[w][i][2 * l] = bf_up(qd & 0xffffu);
    qs[w][i][2 * l + 1] = bf_up(qd >> 16);
    ks[w][i][2 * l] = bf_up(kd & 0xffffu);
    ks[w][i][2 * l + 1] = bf_up(kd >> 16);
    vf0[i] = bf_up(vd & 0xffffu);
    vf1[i] = bf_up(vd >> 16);
  }
  __syncthreads();
  const int si = l >> 3, sj = l & 7;
  float s = 0.f;
#pragma unroll 16
  for (int c = 0; c < 128; ++c) s += qs[w][si][c] * ks[w][sj][c];
  s *= 0.08838834764831845f;  // 1/sqrt(128) = scale^2
  float mx = s;
  mx = fmaxf(mx, __shfl_xor(mx, 1));
  mx = fmaxf(mx, __shfl_xor(mx, 2));
  mx = fmaxf(mx, __shfl_xor(mx, 4));
  float p = __expf(s - mx);
  float sum = p;
  sum += __shfl_xor(sum, 1);
  sum += __shfl_xor(sum, 2);
  sum += __shfl_xor(sum, 4);
  ps[w][si * 8 + sj] = p / sum;
  __syncthreads();
#pragma unroll
  for (int i = 0; i < 8; ++i) {
    float o0 = 0.f, o1 = 0.f;
#pragma unroll
    for (int j = 0; j < 8; ++j) {
      float pw = ps[w][i * 8 + j];
      o0 += pw * vf0[j];
      o1 += pw * vf1[j];
    }
    u32 pk = bf_rne(o0) | (bf_rne(o1) << 16);
    *(u32*)(O + tok * 1024 + i * 128 + 2 * l) = pk;
  }
}

// ---------------- launcher ----------------
extern "C" void kernel_launch(void* const* d_in, const int* in_sizes, int n_in,
                              void* d_out, int out_size, void* d_ws, size_t ws_size,
                              hipStream_t stream) {
  const float* x = (const float*)d_in[0];
  const float* c = (const float*)d_in[1];
  const float* Wq = (const float*)d_in[2];
  const float* Wk = (const float*)d_in[3];
  const float* Wv = (const float*)d_in[4];
  const float* Wout = (const float*)d_in[5];
  const float* bout = (const float*)d_in[6];
  float* out = (float*)d_out;

  const int M = 32768;  // B * CLIP_LEN tokens
  const int N = 1024, Kd = 1024;

  char* ws = (char*)d_ws;
  size_t off = 0;
  auto alloc = [&](size_t bytes) -> void* {
    void* p = ws + off;
    off += (bytes + 255) & ~(size_t)255;
    return p;
  };
  u16* WqT = (u16*)alloc((size_t)1024 * 1024 * 2);
  u16* WkT = (u16*)alloc((size_t)1024 * 1024 * 2);
  u16* WvT = (u16*)alloc((size_t)1024 * 1024 * 2);
  u16* WoT = (u16*)alloc((size_t)1024 * 1024 * 2);

  // rows-per-chunk so 5 row-buffers fit in remaining ws
  size_t remain = (ws_size > off + 4096) ? (ws_size - off - 4096) : 0;
  long chMax = (long)(remain / (5 * 1024 * 2));
  int CH = (int)(chMax / 128) * 128;
  if (CH > M) CH = M;
  if (CH <= 0) return;  // workspace hopelessly small

  u16* Xb = (u16*)alloc((size_t)CH * 1024 * 2);
  u16* Cb = (u16*)alloc((size_t)CH * 1024 * 2);
  u16* Qb = (u16*)alloc((size_t)CH * 1024 * 2);
  u16* Kb = (u16*)alloc((size_t)CH * 1024 * 2);
  u16* Vb = (u16*)alloc((size_t)CH * 1024 * 2);
  u16* Ab = Xb;  // attn output aliases Xb (dead after Q GEMM; stream-ordered)

  transW_k<<<dim3(32, 32, 4), 256, 0, stream>>>(Wq, Wk, Wv, Wout, WqT, WkT, WvT, WoT);

  for (int m0 = 0; m0 < M; m0 += CH) {
    int mm = (M - m0 < CH) ? (M - m0) : CH;
    int n8 = mm * 128;  // elems/8
    cast_bf16_k<<<n8 / 256, 256, 0, stream>>>(x + (size_t)m0 * 1024, Xb, n8);
    cast_bf16_k<<<n8 / 256, 256, 0, stream>>>(c + (size_t)m0 * 1024, Cb, n8);
    dim3 gg(N / 128, mm / 128);
    gemm_bt<0><<<gg, 256, 0, stream>>>(Xb, WqT, Qb, nullptr, mm, N, Kd);
    gemm_bt<0><<<gg, 256, 0, stream>>>(Cb, WkT, Kb, nullptr, mm, N, Kd);
    gemm_bt<0><<<gg, 256, 0, stream>>>(Cb, WvT, Vb, nullptr, mm, N, Kd);
    attn8_k<<<mm / 4, 256, 0, stream>>>(Qb, Kb, Vb, Ab);
    gemm_bt<1><<<gg, 256, 0, stream>>>(Ab, WoT, out + (size_t)m0 * 1024, bout, mm, N, Kd);
  }
}